// Round 8
// baseline (214.275 us; speedup 1.0000x reference)
//
#include <hip/hip_runtime.h>
#include <math.h>

#define N_NODES 100000
#define DIMS 128
#define RS 136   // W16 LDS row stride in halves (272 B): balanced-bank b128 reads
#define CS 136   // epilogue LDS row stride in halves
#define NSTRIPS ((N_NODES + 63) / 64)   // 1563
#define WZ_BLOCKS 521                   // 521 * 3 = 1563: 3 strips per block

typedef _Float16 f16_t;
typedef f16_t half4 __attribute__((ext_vector_type(4)));
typedef f16_t f16x8 __attribute__((ext_vector_type(8)));
typedef float f32x4 __attribute__((ext_vector_type(4)));

__device__ __forceinline__ f16x8 cvt8(float4 a, float4 b) {
    f16x8 h = { (f16_t)a.x, (f16_t)a.y, (f16_t)a.z, (f16_t)a.w,
                (f16_t)b.x, (f16_t)b.y, (f16_t)b.z, (f16_t)b.w };
    return h;
}

// wz16 = (fp16)(z @ W^T + b), z16 = (fp16)z, via mfma_f32_16x16x32_f16.
// R7 structure, but W is staged ONCE per block and amortized over 3 grid-stride
// 64-row strips (521 blocks x 3 strips = 1563). All per-strip phases are
// wave-local (no barrier after the initial staging one).
__global__ __launch_bounds__(256, 2)
void wz_kernel(const float* __restrict__ z, const float* __restrict__ W,
               const float* __restrict__ b,
               f16_t* __restrict__ z16, f16_t* __restrict__ wz16) {
    __shared__ f16_t wl[DIMS * RS];     // 34816 B
    __shared__ f16_t cl[4][16 * CS];    // 17408 B
    const int t    = threadIdx.x;
    const int lane = t & 63;
    const int wave = t >> 6;
    const int m    = lane & 15;
    const int quad = lane >> 4;

    // Stage W -> fp16 LDS once per block: 128x128 = 4096 float4, 16/thread.
    #pragma unroll
    for (int it = 0; it < 16; ++it) {
        int f  = it * 256 + t;
        int r  = f >> 5;             // W row (output col) 0..127
        int i4 = (f & 31) << 2;      // k offset 0..124
        float4 v = *(const float4*)(W + r * DIMS + i4);
        half4 h = { (f16_t)v.x, (f16_t)v.y, (f16_t)v.z, (f16_t)v.w };
        *(half4*)(wl + r * RS + i4) = h;
    }
    __syncthreads();

    for (int s = blockIdx.x; s < NSTRIPS; s += gridDim.x) {
        const int r0    = s * 64 + wave * 16;   // this wave's 16-row strip
        const int arow  = r0 + m;
        const int garow = arow < N_NODES ? arow : N_NODES - 1;   // clamp loads

        // A-frags for K=128 (4 chunks of 32), fused z16 emission.
        f16x8 afrag[4];
        #pragma unroll
        for (int c = 0; c < 4; ++c) {
            const int k0 = c * 32 + quad * 8;
            float4 v0 = *(const float4*)(z + (size_t)garow * DIMS + k0);
            float4 v1 = *(const float4*)(z + (size_t)garow * DIMS + k0 + 4);
            afrag[c] = cvt8(v0, v1);
            if (arow < N_NODES)
                *(f16x8*)(z16 + (size_t)arow * DIMS + k0) = afrag[c];
        }

        // 8 column tiles x 4 k-chunks of MFMA; B-frags from LDS.
        f32x4 acc[8];
        #pragma unroll
        for (int nt = 0; nt < 8; ++nt) acc[nt] = (f32x4){0.f, 0.f, 0.f, 0.f};

        #pragma unroll
        for (int nt = 0; nt < 8; ++nt) {
            #pragma unroll
            for (int c = 0; c < 4; ++c) {
                f16x8 bfrag = *(const f16x8*)(wl + (nt * 16 + m) * RS + c * 32 + quad * 8);
                acc[nt] = __builtin_amdgcn_mfma_f32_16x16x32_f16(afrag[c], bfrag, acc[nt], 0, 0, 0);
            }
        }

        // Epilogue: bias + cvt -> wave-local LDS transpose -> coalesced stores.
        // Same-wave ds_write -> ds_read is ordered; cl[wave] is wave-private.
        f16_t* my = cl[wave];
        #pragma unroll
        for (int nt = 0; nt < 8; ++nt) {
            const float bv = b[nt * 16 + m];
            #pragma unroll
            for (int r = 0; r < 4; ++r)
                my[(quad * 4 + r) * CS + nt * 16 + m] = (f16_t)(acc[nt][r] + bv);
        }
        #pragma unroll
        for (int p = 0; p < 4; ++p) {
            const int rr = p * 4 + (lane >> 4);
            const int cc = (lane & 15) * 8;
            const int gr = r0 + rr;
            if (gr < N_NODES)
                *(f16x8*)(wz16 + (size_t)gr * DIMS + cc) = *(const f16x8*)(my + rr * CS + cc);
        }
    }
}

__device__ __forceinline__ float dot4h(half4 a, half4 w) {
    return fmaf((float)a.x, (float)w.x,
           fmaf((float)a.y, (float)w.y,
           fmaf((float)a.z, (float)w.z, (float)a.w * (float)w.w)));
}

// 4 edges per 32-lane group; fp16 rows (256 B each, 8 B per lane). UNCHANGED.
__global__ __launch_bounds__(256)
void edge_kernel(const f16_t* __restrict__ z16, const f16_t* __restrict__ wz16,
                 const int* __restrict__ src, const int* __restrict__ dst,
                 float* __restrict__ out, int E) {
    const int t = blockIdx.x * 256 + threadIdx.x;
    const int g = t >> 5;
    const int l = t & 31;
    const int e0 = g << 2;
    if (e0 >= E) return;

    const int4 s4 = *(const int4*)(src + e0);
    const int4 d4 = *(const int4*)(dst + e0);

    half4 a0 = ((const half4*)(z16  + (size_t)s4.x * DIMS))[l];
    half4 a1 = ((const half4*)(z16  + (size_t)s4.y * DIMS))[l];
    half4 a2 = ((const half4*)(z16  + (size_t)s4.z * DIMS))[l];
    half4 a3 = ((const half4*)(z16  + (size_t)s4.w * DIMS))[l];
    half4 w0 = ((const half4*)(wz16 + (size_t)d4.x * DIMS))[l];
    half4 w1 = ((const half4*)(wz16 + (size_t)d4.y * DIMS))[l];
    half4 w2 = ((const half4*)(wz16 + (size_t)d4.z * DIMS))[l];
    half4 w3 = ((const half4*)(wz16 + (size_t)d4.w * DIMS))[l];

    float p0 = dot4h(a0, w0);
    float p1 = dot4h(a1, w1);
    float p2 = dot4h(a2, w2);
    float p3 = dot4h(a3, w3);

    #pragma unroll
    for (int o = 16; o >= 1; o >>= 1) {
        p0 += __shfl_xor(p0, o);
        p1 += __shfl_xor(p1, o);
        p2 += __shfl_xor(p2, o);
        p3 += __shfl_xor(p3, o);
    }

    if (l == 0) {
        float4 r;
        r.x = 1.0f / (1.0f + __expf(-p0));
        r.y = 1.0f / (1.0f + __expf(-p1));
        r.z = 1.0f / (1.0f + __expf(-p2));
        r.w = 1.0f / (1.0f + __expf(-p3));
        *(float4*)(out + e0) = r;
    }
}

extern "C" void kernel_launch(void* const* d_in, const int* in_sizes, int n_in,
                              void* d_out, int out_size, void* d_ws, size_t ws_size,
                              hipStream_t stream) {
    const float* z  = (const float*)d_in[0];
    const int*   ei = (const int*)d_in[1];   // [2, E] int32
    const float* W  = (const float*)d_in[2];
    const float* b  = (const float*)d_in[3];
    float* out = (float*)d_out;

    const int E = in_sizes[1] / 2;

    f16_t* z16  = (f16_t*)d_ws;                                       // 25.6 MB
    f16_t* wz16 = (f16_t*)((char*)d_ws + (size_t)N_NODES * DIMS * 2); // 25.6 MB

    wz_kernel<<<WZ_BLOCKS, 256, 0, stream>>>(z, W, b, z16, wz16);

    const int groups = (E + 3) / 4;                 // 400000 (E % 4 == 0)
    const int total  = groups * 32;
    edge_kernel<<<(total + 255) / 256, 256, 0, stream>>>(z16, wz16, ei, ei + E, out, E);
}

// Round 10
// 210.001 us; speedup vs baseline: 1.0204x; 1.0204x over previous
//
#include <hip/hip_runtime.h>
#include <math.h>

#define N_NODES 100000
#define DIMS 128
#define RS 136   // W16 LDS row stride in halves (272 B): balanced-bank b128 reads
#define CS 136   // epilogue LDS row stride in halves

typedef _Float16 f16_t;
typedef f16_t half4 __attribute__((ext_vector_type(4)));
typedef f16_t f16x8 __attribute__((ext_vector_type(8)));
typedef float f32x4 __attribute__((ext_vector_type(4)));

__device__ __forceinline__ f16x8 cvt8(float4 a, float4 b) {
    f16x8 h = { (f16_t)a.x, (f16_t)a.y, (f16_t)a.z, (f16_t)a.w,
                (f16_t)b.x, (f16_t)b.y, (f16_t)b.z, (f16_t)b.w };
    return h;
}

// wz16 = (fp16)(z @ W^T + b), z16 = (fp16)z, via mfma_f32_16x16x32_f16.
// R5 structure (LDS-staged fp16 W + fused A-frag/z16 emission) + R6's
// wave-local LDS-transpose epilogue (coalesced 16B wz16 stores, no barrier:
// same-wave DS ops are ordered and cl[wave] is wave-private).  [= R7 exactly]
__global__ __launch_bounds__(256, 2)
void wz_kernel(const float* __restrict__ z, const float* __restrict__ W,
               const float* __restrict__ b,
               f16_t* __restrict__ z16, f16_t* __restrict__ wz16) {
    __shared__ f16_t wl[DIMS * RS];     // 34816 B
    __shared__ f16_t cl[4][16 * CS];    // 17408 B  (52.2 KB total)
    const int t    = threadIdx.x;
    const int lane = t & 63;
    const int wave = t >> 6;
    const int m    = lane & 15;
    const int quad = lane >> 4;

    // Stage W -> fp16 LDS: 128x128 = 4096 float4 chunks, 16 per thread.
    #pragma unroll
    for (int it = 0; it < 16; ++it) {
        int f  = it * 256 + t;
        int r  = f >> 5;             // W row (output col) 0..127
        int i4 = (f & 31) << 2;      // k offset 0..124
        float4 v = *(const float4*)(W + r * DIMS + i4);
        half4 h = { (f16_t)v.x, (f16_t)v.y, (f16_t)v.z, (f16_t)v.w };
        *(half4*)(wl + r * RS + i4) = h;
    }
    __syncthreads();

    const int r0    = blockIdx.x * 64 + wave * 16;   // wave's 16-row strip
    const int arow  = r0 + m;
    const int garow = arow < N_NODES ? arow : N_NODES - 1;   // clamp loads

    // A-frags for K=128 (4 chunks of 32), fused z16 emission.
    f16x8 afrag[4];
    #pragma unroll
    for (int c = 0; c < 4; ++c) {
        const int k0 = c * 32 + quad * 8;
        float4 v0 = *(const float4*)(z + (size_t)garow * DIMS + k0);
        float4 v1 = *(const float4*)(z + (size_t)garow * DIMS + k0 + 4);
        afrag[c] = cvt8(v0, v1);
        if (arow < N_NODES)
            *(f16x8*)(z16 + (size_t)arow * DIMS + k0) = afrag[c];
    }

    // 8 column tiles x 4 k-chunks of MFMA; B-frags from LDS.
    f32x4 acc[8];
    #pragma unroll
    for (int nt = 0; nt < 8; ++nt) acc[nt] = (f32x4){0.f, 0.f, 0.f, 0.f};

    #pragma unroll
    for (int nt = 0; nt < 8; ++nt) {
        #pragma unroll
        for (int c = 0; c < 4; ++c) {
            f16x8 bfrag = *(const f16x8*)(wl + (nt * 16 + m) * RS + c * 32 + quad * 8);
            acc[nt] = __builtin_amdgcn_mfma_f32_16x16x32_f16(afrag[c], bfrag, acc[nt], 0, 0, 0);
        }
    }

    // Epilogue: bias + cvt -> wave-local LDS transpose -> coalesced 16B stores.
    f16_t* my = cl[wave];
    #pragma unroll
    for (int nt = 0; nt < 8; ++nt) {
        const float bv = b[nt * 16 + m];
        #pragma unroll
        for (int r = 0; r < 4; ++r)
            my[(quad * 4 + r) * CS + nt * 16 + m] = (f16_t)(acc[nt][r] + bv);
    }
    #pragma unroll
    for (int p = 0; p < 4; ++p) {
        const int rr = p * 4 + (lane >> 4);
        const int cc = (lane & 15) * 8;
        const int gr = r0 + rr;
        if (gr < N_NODES)
            *(f16x8*)(wz16 + (size_t)gr * DIMS + cc) = *(const f16x8*)(my + rr * CS + cc);
    }
}

__device__ __forceinline__ float dot4h(half4 a, half4 w) {
    return fmaf((float)a.x, (float)w.x,
           fmaf((float)a.y, (float)w.y,
           fmaf((float)a.z, (float)w.z, (float)a.w * (float)w.w)));
}

// 4 edges per 32-lane group; fp16 rows (256 B each, 8 B per lane).
__global__ __launch_bounds__(256)
void edge_kernel(const f16_t* __restrict__ z16, const f16_t* __restrict__ wz16,
                 const int* __restrict__ src, const int* __restrict__ dst,
                 float* __restrict__ out, int E) {
    const int t = blockIdx.x * 256 + threadIdx.x;
    const int g = t >> 5;
    const int l = t & 31;
    const int e0 = g << 2;
    if (e0 >= E) return;

    const int4 s4 = *(const int4*)(src + e0);
    const int4 d4 = *(const int4*)(dst + e0);

    half4 a0 = ((const half4*)(z16  + (size_t)s4.x * DIMS))[l];
    half4 a1 = ((const half4*)(z16  + (size_t)s4.y * DIMS))[l];
    half4 a2 = ((const half4*)(z16  + (size_t)s4.z * DIMS))[l];
    half4 a3 = ((const half4*)(z16  + (size_t)s4.w * DIMS))[l];
    half4 w0 = ((const half4*)(wz16 + (size_t)d4.x * DIMS))[l];
    half4 w1 = ((const half4*)(wz16 + (size_t)d4.y * DIMS))[l];
    half4 w2 = ((const half4*)(wz16 + (size_t)d4.z * DIMS))[l];
    half4 w3 = ((const half4*)(wz16 + (size_t)d4.w * DIMS))[l];

    float p0 = dot4h(a0, w0);
    float p1 = dot4h(a1, w1);
    float p2 = dot4h(a2, w2);
    float p3 = dot4h(a3, w3);

    #pragma unroll
    for (int o = 16; o >= 1; o >>= 1) {
        p0 += __shfl_xor(p0, o);
        p1 += __shfl_xor(p1, o);
        p2 += __shfl_xor(p2, o);
        p3 += __shfl_xor(p3, o);
    }

    if (l == 0) {
        float4 r;
        r.x = 1.0f / (1.0f + __expf(-p0));
        r.y = 1.0f / (1.0f + __expf(-p1));
        r.z = 1.0f / (1.0f + __expf(-p2));
        r.w = 1.0f / (1.0f + __expf(-p3));
        *(float4*)(out + e0) = r;
    }
}

extern "C" void kernel_launch(void* const* d_in, const int* in_sizes, int n_in,
                              void* d_out, int out_size, void* d_ws, size_t ws_size,
                              hipStream_t stream) {
    const float* z  = (const float*)d_in[0];
    const int*   ei = (const int*)d_in[1];   // [2, E] int32
    const float* W  = (const float*)d_in[2];
    const float* b  = (const float*)d_in[3];
    float* out = (float*)d_out;

    const int E = in_sizes[1] / 2;

    f16_t* z16  = (f16_t*)d_ws;                                       // 25.6 MB
    f16_t* wz16 = (f16_t*)((char*)d_ws + (size_t)N_NODES * DIMS * 2); // 25.6 MB

    const int row_blocks = (N_NODES + 63) / 64;     // 1563
    wz_kernel<<<row_blocks, 256, 0, stream>>>(z, W, b, z16, wz16);

    const int groups = (E + 3) / 4;                 // 400000 (E % 4 == 0)
    const int total  = groups * 32;
    edge_kernel<<<(total + 255) / 256, 256, 0, stream>>>(z16, wz16, ei, ei + E, out, E);
}